// Round 16
// baseline (439.169 us; speedup 1.0000x reference)
//
#include <hip/hip_runtime.h>
#include <math.h>

#define GS    512   // nodes per group
#define GSH   9
#define NGMAX 128   // max groups per branch (G1=98 for N=50000)
#define FCAP  48    // LDS FIFO capacity per group per round
#define SCAP  10240 // group region capacity

// ---------------- pass 1: bin edges into 512-node groups ----------------

__global__ __launch_bounds__(1024) void bin_kernel(
    const int* __restrict__ s1, const int* __restrict__ d1,
    const int* __restrict__ s2, const int* __restrict__ d2,
    int* __restrict__ gcur, int* __restrict__ pairs, int E, int G1) {
  __shared__ int fifo[NGMAX][FCAP];
  __shared__ int fcnt[NGMAX];
  __shared__ int fbase[NGMAX];
  __shared__ int fpre[NGMAX + 1];
  const int* src = blockIdx.y ? s2 : s1;
  const int* dst = blockIdx.y ? d2 : d1;
  int gboff = blockIdx.y * G1;
  int tid = threadIdx.x;
  if (tid < NGMAX) fcnt[tid] = 0;
  __syncthreads();
  int e0 = blockIdx.x * 4096;
  for (int r = 0; r < 4; ++r) {
    int e = e0 + r * 1024 + tid;
    if (e < E) {
      int s = src[e], d = dst[e];
      int g = d >> GSH;
      int pk = s | ((d & (GS - 1)) << 17);
      int pos = atomicAdd(&fcnt[g], 1);
      if (pos < FCAP) fifo[g][pos] = pk;
      else {
        int gp = atomicAdd(&gcur[gboff + g], 1);
        pairs[(size_t)(gboff + g) * SCAP + gp] = pk;
      }
    }
    __syncthreads();
    if (tid < G1) {
      int c = fcnt[tid];
      if (c > FCAP) c = FCAP;
      fcnt[tid] = c;
      fbase[tid] = (c > 0) ? atomicAdd(&gcur[gboff + tid], c) : 0;
    }
    __syncthreads();
    if (tid == 0) {
      int acc = 0;
      for (int i = 0; i < G1; ++i) { fpre[i] = acc; acc += fcnt[i]; }
      fpre[G1] = acc;
    }
    __syncthreads();
    int T = fpre[G1];
    for (int t = tid; t < T; t += 1024) {
      int lo = 0, hi = G1;
      while (hi - lo > 1) { int mid = (lo + hi) >> 1; if (fpre[mid] <= t) lo = mid; else hi = mid; }
      int idx = t - fpre[lo];
      pairs[(size_t)(gboff + lo) * SCAP + fbase[lo] + idx] = fifo[lo][idx];
    }
    __syncthreads();
    if (tid < NGMAX) fcnt[tid] = 0;
    __syncthreads();
  }
}

// ---------------- pass 2: per-group node CSR, in-place ----------------

__global__ __launch_bounds__(1024) void refine_kernel(
    const int* __restrict__ gcur, int* __restrict__ pairs,
    int* __restrict__ offs, int* __restrict__ counts, int N, int G1) {
  __shared__ int stg[SCAP];
  __shared__ int hist[GS];
  __shared__ int excl[GS];
  __shared__ int wtot[8];
  int gl = blockIdx.x, br = blockIdx.y;
  int g = br * G1 + gl;
  size_t rbase = (size_t)g * SCAP;
  int rcnt = gcur[g];
  if (rcnt > SCAP) rcnt = SCAP;
  int tid = threadIdx.x;
  if (tid < GS) hist[tid] = 0;
  __syncthreads();
  for (int i = tid; i < rcnt; i += 1024) {
    int pk = pairs[rbase + i];
    stg[i] = pk;
    atomicAdd(&hist[pk >> 17], 1);
  }
  __syncthreads();
  if (tid < GS) {
    int lane = tid & 63, wv = tid >> 6;
    int v = hist[tid];
    int inc = v;
    #pragma unroll
    for (int off = 1; off < 64; off <<= 1) {
      int t = __shfl_up(inc, off);
      if (lane >= off) inc += t;
    }
    excl[tid] = inc - v;
    if (lane == 63) wtot[wv] = inc;
  }
  __syncthreads();
  if (tid == 0) {
    int a = 0;
    #pragma unroll
    for (int w = 0; w < 8; ++w) { int t = wtot[w]; wtot[w] = a; a += t; }
  }
  __syncthreads();
  if (tid < GS) excl[tid] += wtot[tid >> 6];
  __syncthreads();
  int node0 = gl * GS;
  int nloc = N - node0; if (nloc > GS) nloc = GS;
  for (int j = tid; j < nloc; j += 1024) {
    offs[br * N + node0 + j] = (int)rbase + excl[j];
    counts[br * N + node0 + j] = hist[j];
  }
  __syncthreads();
  for (int i = tid; i < rcnt; i += 1024) {
    int pk = stg[i];
    int pos = atomicAdd(&excl[pk >> 17], 1);
    pairs[rbase + pos] = pk & 0x1FFFF;
  }
}

// ---------------- GEMM both branches (proven R15 config) ----------------

template <int COUT>
__global__ __launch_bounds__(256, 2) void gemm2_kernel(
    const float* __restrict__ X0, const float* __restrict__ X1,
    const float* __restrict__ W0, const float* __restrict__ W1,
    const float* __restrict__ bias0, const float* __restrict__ bias1,
    float* __restrict__ Y0, float* __restrict__ Y1, int nrows) {
  constexpr int CG = COUT / 4;
  constexpr int RG = 256 / CG;
  constexpr int BM = 64;
  constexpr int RPT = BM / RG;
  const float* X = blockIdx.y ? X1 : X0;
  const float* W = blockIdx.y ? W1 : W0;
  const float* bias = blockIdx.y ? bias1 : bias0;
  float* Y = blockIdx.y ? Y1 : Y0;
  __shared__ float xs[BM][128];
  int tid = threadIdx.x;
  int block_row = blockIdx.x * BM;
  for (int i = tid; i < BM * 32; i += 256) {
    int r = i >> 5, c4 = i & 31;
    int gr = block_row + r;
    float4 v = make_float4(0.f, 0.f, 0.f, 0.f);
    if (gr < nrows) v = reinterpret_cast<const float4*>(X + (size_t)gr * 128)[c4];
    *reinterpret_cast<float4*>(&xs[r][c4 * 4]) = v;
  }
  __syncthreads();
  int c0 = (tid % CG) * 4;
  int r0 = (tid / CG) * RPT;
  float acc[RPT][4] = {};
  #pragma unroll 2
  for (int k = 0; k < 128; k += 4) {
    float4 w0 = *reinterpret_cast<const float4*>(&W[(k + 0) * COUT + c0]);
    float4 w1 = *reinterpret_cast<const float4*>(&W[(k + 1) * COUT + c0]);
    float4 w2 = *reinterpret_cast<const float4*>(&W[(k + 2) * COUT + c0]);
    float4 w3 = *reinterpret_cast<const float4*>(&W[(k + 3) * COUT + c0]);
    #pragma unroll
    for (int i = 0; i < RPT; ++i) {
      float4 x = *reinterpret_cast<const float4*>(&xs[r0 + i][k]);
      acc[i][0] = fmaf(x.x, w0.x, acc[i][0]);
      acc[i][1] = fmaf(x.x, w0.y, acc[i][1]);
      acc[i][2] = fmaf(x.x, w0.z, acc[i][2]);
      acc[i][3] = fmaf(x.x, w0.w, acc[i][3]);
      acc[i][0] = fmaf(x.y, w1.x, acc[i][0]);
      acc[i][1] = fmaf(x.y, w1.y, acc[i][1]);
      acc[i][2] = fmaf(x.y, w1.z, acc[i][2]);
      acc[i][3] = fmaf(x.y, w1.w, acc[i][3]);
      acc[i][0] = fmaf(x.z, w2.x, acc[i][0]);
      acc[i][1] = fmaf(x.z, w2.y, acc[i][1]);
      acc[i][2] = fmaf(x.z, w2.z, acc[i][2]);
      acc[i][3] = fmaf(x.z, w2.w, acc[i][3]);
      acc[i][0] = fmaf(x.w, w3.x, acc[i][0]);
      acc[i][1] = fmaf(x.w, w3.y, acc[i][1]);
      acc[i][2] = fmaf(x.w, w3.z, acc[i][2]);
      acc[i][3] = fmaf(x.w, w3.w, acc[i][3]);
    }
  }
  float4 bv = *reinterpret_cast<const float4*>(&bias[c0]);
  #pragma unroll
  for (int i = 0; i < RPT; ++i) {
    int gr = block_row + r0 + i;
    if (gr < nrows) {
      float4 o;
      o.x = acc[i][0] + bv.x; o.y = acc[i][1] + bv.y;
      o.z = acc[i][2] + bv.z; o.w = acc[i][3] + bv.w;
      *reinterpret_cast<float4*>(&Y[(size_t)gr * COUT + c0]) = o;
    }
  }
}

// ---------------- XCD-sliced aggregate + BN + relu ----------------
// slice = blockIdx.x % NSL pins a 16-col (3.2MB) table slice to one XCD's L2
// (round-robin block->XCD): each XCD reads the table ~once. Lane layout:
// 16 nodes/wave x (4 lanes x float4 = 16 cols) -> 16 edges per load instr,
// no cross-lane reduce. Idx batched 4/group for MLP.

template <int C, int NSL>
__global__ __launch_bounds__(1024) void agg_sl_kernel(
    const float* __restrict__ h, const int* __restrict__ offs,
    const int* __restrict__ counts, const int* __restrict__ csr,
    const float* __restrict__ gamma, const float* __restrict__ beta,
    float* __restrict__ out, int n) {
  int slice = blockIdx.x & (NSL - 1);
  int nodeblk = blockIdx.x / NSL;
  int tid = threadIdx.x;
  int wv = tid >> 6, lane = tid & 63;
  int grp = lane >> 2, c4 = lane & 3;
  int node = nodeblk * 256 + wv * 16 + grp;
  bool live = node < n;
  int nd = live ? node : n - 1;
  int beg = offs[nd];
  int cnt = live ? counts[nd] : 0;
  int elast = cnt > 0 ? cnt - 1 : 0;
  int mx = cnt;  // wave-max cnt over the 16 groups
  #pragma unroll
  for (int off = 4; off < 64; off <<= 1) {
    int t = __shfl_xor(mx, off);
    mx = t > mx ? t : mx;
  }
  const float* hp = h + slice * 16 + c4 * 4;
  float4 a = make_float4(0.f, 0.f, 0.f, 0.f);
  for (int eb = 0; eb < mx; eb += 4) {
    int ee = eb + c4;
    ee = ee < elast ? ee : elast;
    int idx = csr[beg + ee];     // 4 idx per group, coalesced within node span
    #pragma unroll
    for (int u = 0; u < 4; ++u) {
      int s = __shfl(idx, grp * 4 + u);
      float4 v = *reinterpret_cast<const float4*>(hp + (size_t)s * C);
      bool ok = (eb + u) < cnt;
      a.x += ok ? v.x : 0.f;
      a.y += ok ? v.y : 0.f;
      a.z += ok ? v.z : 0.f;
      a.w += ok ? v.w : 0.f;
    }
  }
  if (live) {
    const float inv = 1.0f / sqrtf(1.0f + 1.0e-3f);
    float4 gv = *reinterpret_cast<const float4*>(gamma + slice * 16 + c4 * 4);
    float4 bv = *reinterpret_cast<const float4*>(beta + slice * 16 + c4 * 4);
    float4 o;
    o.x = fmaxf(fmaf(a.x, gv.x * inv, bv.x), 0.f);
    o.y = fmaxf(fmaf(a.y, gv.y * inv, bv.y), 0.f);
    o.z = fmaxf(fmaf(a.z, gv.z * inv, bv.z), 0.f);
    o.w = fmaxf(fmaf(a.w, gv.w * inv, bv.w), 0.f);
    *reinterpret_cast<float4*>(out + (size_t)node * C + slice * 16 + c4 * 4) = o;
  }
}

// ---------------- Segment mean pool, both branches ----------------

__global__ __launch_bounds__(1024) void pool2_kernel(
    const float* __restrict__ h0, const float* __restrict__ h1,
    const int* __restrict__ seg0, const int* __restrict__ seg1,
    float* __restrict__ p, int n) {
  const float* h = blockIdx.y ? h1 : h0;
  const int* seg = blockIdx.y ? seg1 : seg0;
  float* pb = p + blockIdx.y * 64 * 64;
  int g = blockIdx.x;
  int lo, hi;
  { int l = 0, r = n; while (l < r) { int m = (l + r) >> 1; if (seg[m] < g) l = m + 1; else r = m; } lo = l; }
  { int l = 0, r = n; while (l < r) { int m = (l + r) >> 1; if (seg[m] < g + 1) l = m + 1; else r = m; } hi = l; }
  int c = threadIdx.x & 63;
  int sub = threadIdx.x >> 6;
  float acc = 0.f;
  for (int i = lo + sub; i < hi; i += 16) acc += h[(size_t)i * 64 + c];
  __shared__ float red[16][64];
  red[sub][c] = acc;
  __syncthreads();
  if (sub == 0) {
    float s = 0.f;
    #pragma unroll
    for (int k = 0; k < 16; ++k) s += red[k][c];
    float cnt = (float)(hi - lo);
    pb[g * 64 + c] = s / fmaxf(cnt, 1.0f);
  }
}

// ---------------- Head ----------------

__global__ __launch_bounds__(512) void head_kernel(const float* __restrict__ p,
                                                   const float* __restrict__ Wd,
                                                   const float* __restrict__ bd,
                                                   const float* __restrict__ Wo,
                                                   const float* __restrict__ bo,
                                                   float* __restrict__ out) {
  __shared__ float cur[64][128];
  __shared__ float nxt[64][128];
  int tid = threadIdx.x;
  const float* p1 = p;
  const float* p2 = p + 64 * 64;
  for (int i = tid; i < 64 * 128; i += 512) {
    int r = i >> 7, c = i & 127;
    cur[r][c] = (c < 64) ? p1[r * 64 + c] : p2[r * 64 + (c - 64)];
  }
  __syncthreads();
  int c0 = (tid & 31) * 4;
  int r0 = (tid >> 5) * 4;
  for (int layer = 0; layer < 2; ++layer) {
    float acc[4][4] = {};
    #pragma unroll 4
    for (int k = 0; k < 128; ++k) {
      float4 w = *reinterpret_cast<const float4*>(&Wd[k * 128 + c0]);
      #pragma unroll
      for (int i = 0; i < 4; ++i) {
        float x = cur[r0 + i][k];
        acc[i][0] = fmaf(x, w.x, acc[i][0]);
        acc[i][1] = fmaf(x, w.y, acc[i][1]);
        acc[i][2] = fmaf(x, w.z, acc[i][2]);
        acc[i][3] = fmaf(x, w.w, acc[i][3]);
      }
    }
    float4 bv = *reinterpret_cast<const float4*>(&bd[c0]);
    __syncthreads();
    #pragma unroll
    for (int i = 0; i < 4; ++i) {
      float4 o;
      o.x = fmaxf(acc[i][0] + bv.x, 0.f);
      o.y = fmaxf(acc[i][1] + bv.y, 0.f);
      o.z = fmaxf(acc[i][2] + bv.z, 0.f);
      o.w = fmaxf(acc[i][3] + bv.w, 0.f);
      *reinterpret_cast<float4*>(&nxt[r0 + i][c0]) = o;
    }
    __syncthreads();
    for (int i = tid; i < 64 * 128; i += 512) (&cur[0][0])[i] = (&nxt[0][0])[i];
    __syncthreads();
  }
  int wv = tid >> 6, lane = tid & 63;
  for (int r = wv; r < 64; r += 8) {
    float v = cur[r][lane] * Wo[lane] + cur[r][64 + lane] * Wo[64 + lane];
    #pragma unroll
    for (int off = 32; off; off >>= 1) v += __shfl_down(v, off);
    if (lane == 0) out[r] = 1.0f / (1.0f + expf(-(v + bo[0])));
  }
}

// ---------------- launch ----------------

extern "C" void kernel_launch(void* const* d_in, const int* in_sizes, int n_in,
                              void* d_out, int out_size, void* d_ws, size_t ws_size,
                              hipStream_t stream) {
  const float* x1  = (const float*)d_in[0];
  const float* x2  = (const float*)d_in[1];
  const int* e1    = (const int*)d_in[2];
  const int* e2    = (const int*)d_in[3];
  const int* seg1  = (const int*)d_in[4];
  const int* seg2  = (const int*)d_in[5];
  const float* W1a = (const float*)d_in[6];  const float* b1a = (const float*)d_in[7];
  const float* g1a = (const float*)d_in[8];  const float* be1a = (const float*)d_in[9];
  const float* W1b = (const float*)d_in[10]; const float* b1b = (const float*)d_in[11];
  const float* g1b = (const float*)d_in[12]; const float* be1b = (const float*)d_in[13];
  const float* W2a = (const float*)d_in[14]; const float* b2a = (const float*)d_in[15];
  const float* g2a = (const float*)d_in[16]; const float* be2a = (const float*)d_in[17];
  const float* W2b = (const float*)d_in[18]; const float* b2b = (const float*)d_in[19];
  const float* g2b = (const float*)d_in[20]; const float* be2b = (const float*)d_in[21];
  const float* Wd  = (const float*)d_in[22]; const float* bd  = (const float*)d_in[23];
  const float* Wo  = (const float*)d_in[24]; const float* bo  = (const float*)d_in[25];
  float* out = (float*)d_out;

  const int N = in_sizes[0] / 128;
  const int E = in_sizes[2] / 2;
  const int G1 = (N + GS - 1) >> GSH;
  const int G  = 2 * G1;
  const int NB = (N + 255) / 256;   // node blocks (256 nodes per 1024-thr block)

  char* ws = (char*)d_ws;
  size_t off = 0;
  auto alloc = [&](size_t bytes) -> void* {
    void* ptr = ws + off;
    off += (bytes + 255) & ~(size_t)255;
    return ptr;
  };
  float* h0   = (float*)alloc((size_t)N * 128 * sizeof(float));
  float* h1   = (float*)alloc((size_t)N * 128 * sizeof(float));
  float* ag0  = (float*)alloc((size_t)N * 128 * sizeof(float));
  float* ag1  = (float*)alloc((size_t)N * 128 * sizeof(float));
  int* pairs  = (int*)alloc((size_t)G * SCAP * sizeof(int));
  int* offs   = (int*)alloc((size_t)(2 * N) * sizeof(int));
  int* counts = (int*)alloc((size_t)(2 * N) * sizeof(int));
  int* gcur   = (int*)alloc((size_t)(G + 8) * sizeof(int));
  float* pbuf = (float*)alloc(2 * 64 * 64 * sizeof(float));
  (void)ws_size; (void)n_in; (void)out_size;

  // ---- CSR build ----
  hipMemsetAsync(gcur, 0, (size_t)(G + 8) * sizeof(int), stream);
  {
    dim3 gb((E + 4095) / 4096, 2);
    bin_kernel<<<gb, 1024, 0, stream>>>(e1, e1 + E, e2, e2 + E, gcur, pairs, E, G1);
    dim3 gr(G1, 2);
    refine_kernel<<<gr, 1024, 0, stream>>>(gcur, pairs, offs, counts, N, G1);
  }

  // layer 1
  {
    dim3 gg((N + 63) / 64, 2);
    gemm2_kernel<128><<<gg, 256, 0, stream>>>(x1, x2, W1a, W2a, b1a, b2a, h0, h1, N);
  }
  agg_sl_kernel<128, 8><<<NB * 8, 1024, 0, stream>>>(h0, offs, counts, pairs, g1a, be1a, ag0, N);
  agg_sl_kernel<128, 8><<<NB * 8, 1024, 0, stream>>>(h1, offs + N, counts + N, pairs, g2a, be2a, ag1, N);
  // layer 2
  {
    dim3 gg((N + 63) / 64, 2);
    gemm2_kernel<64><<<gg, 256, 0, stream>>>(ag0, ag1, W1b, W2b, b1b, b2b, h0, h1, N);
  }
  agg_sl_kernel<64, 4><<<NB * 4, 1024, 0, stream>>>(h0, offs, counts, pairs, g1b, be1b, ag0, N);
  agg_sl_kernel<64, 4><<<NB * 4, 1024, 0, stream>>>(h1, offs + N, counts + N, pairs, g2b, be2b, ag1, N);
  // pool + head
  {
    dim3 gp(64, 2);
    pool2_kernel<<<gp, 1024, 0, stream>>>(ag0, ag1, seg1, seg2, pbuf, N);
  }
  head_kernel<<<1, 512, 0, stream>>>(pbuf, Wd, bd, Wo, bo, out);
}

// Round 17
// 425.998 us; speedup vs baseline: 1.0309x; 1.0309x over previous
//
#include <hip/hip_runtime.h>
#include <math.h>

#define GS    512   // nodes per group
#define GSH   9
#define NGMAX 128   // max groups per branch (G1=98 for N=50000)
#define FCAP  48    // LDS FIFO capacity per group per round
#define SCAP  10240 // group region capacity

// ---------------- pass 1: bin edges into 512-node groups ----------------

__global__ __launch_bounds__(1024) void bin_kernel(
    const int* __restrict__ s1, const int* __restrict__ d1,
    const int* __restrict__ s2, const int* __restrict__ d2,
    int* __restrict__ gcur, int* __restrict__ pairs, int E, int G1) {
  __shared__ int fifo[NGMAX][FCAP];
  __shared__ int fcnt[NGMAX];
  __shared__ int fbase[NGMAX];
  __shared__ int fpre[NGMAX + 1];
  const int* src = blockIdx.y ? s2 : s1;
  const int* dst = blockIdx.y ? d2 : d1;
  int gboff = blockIdx.y * G1;
  int tid = threadIdx.x;
  if (tid < NGMAX) fcnt[tid] = 0;
  __syncthreads();
  int e0 = blockIdx.x * 4096;
  for (int r = 0; r < 4; ++r) {
    int e = e0 + r * 1024 + tid;
    if (e < E) {
      int s = src[e], d = dst[e];
      int g = d >> GSH;
      int pk = s | ((d & (GS - 1)) << 17);
      int pos = atomicAdd(&fcnt[g], 1);
      if (pos < FCAP) fifo[g][pos] = pk;
      else {
        int gp = atomicAdd(&gcur[gboff + g], 1);
        pairs[(size_t)(gboff + g) * SCAP + gp] = pk;
      }
    }
    __syncthreads();
    if (tid < G1) {
      int c = fcnt[tid];
      if (c > FCAP) c = FCAP;
      fcnt[tid] = c;
      fbase[tid] = (c > 0) ? atomicAdd(&gcur[gboff + tid], c) : 0;
    }
    __syncthreads();
    if (tid == 0) {
      int acc = 0;
      for (int i = 0; i < G1; ++i) { fpre[i] = acc; acc += fcnt[i]; }
      fpre[G1] = acc;
    }
    __syncthreads();
    int T = fpre[G1];
    for (int t = tid; t < T; t += 1024) {
      int lo = 0, hi = G1;
      while (hi - lo > 1) { int mid = (lo + hi) >> 1; if (fpre[mid] <= t) lo = mid; else hi = mid; }
      int idx = t - fpre[lo];
      pairs[(size_t)(gboff + lo) * SCAP + fbase[lo] + idx] = fifo[lo][idx];
    }
    __syncthreads();
    if (tid < NGMAX) fcnt[tid] = 0;
    __syncthreads();
  }
}

// ---------------- pass 2: per-group node CSR, in-place ----------------

__global__ __launch_bounds__(1024) void refine_kernel(
    const int* __restrict__ gcur, int* __restrict__ pairs,
    int* __restrict__ offs, int* __restrict__ counts, int N, int G1) {
  __shared__ int stg[SCAP];
  __shared__ int hist[GS];
  __shared__ int excl[GS];
  __shared__ int wtot[8];
  int gl = blockIdx.x, br = blockIdx.y;
  int g = br * G1 + gl;
  size_t rbase = (size_t)g * SCAP;
  int rcnt = gcur[g];
  if (rcnt > SCAP) rcnt = SCAP;
  int tid = threadIdx.x;
  if (tid < GS) hist[tid] = 0;
  __syncthreads();
  for (int i = tid; i < rcnt; i += 1024) {
    int pk = pairs[rbase + i];
    stg[i] = pk;
    atomicAdd(&hist[pk >> 17], 1);
  }
  __syncthreads();
  if (tid < GS) {
    int lane = tid & 63, wv = tid >> 6;
    int v = hist[tid];
    int inc = v;
    #pragma unroll
    for (int off = 1; off < 64; off <<= 1) {
      int t = __shfl_up(inc, off);
      if (lane >= off) inc += t;
    }
    excl[tid] = inc - v;
    if (lane == 63) wtot[wv] = inc;
  }
  __syncthreads();
  if (tid == 0) {
    int a = 0;
    #pragma unroll
    for (int w = 0; w < 8; ++w) { int t = wtot[w]; wtot[w] = a; a += t; }
  }
  __syncthreads();
  if (tid < GS) excl[tid] += wtot[tid >> 6];
  __syncthreads();
  int node0 = gl * GS;
  int nloc = N - node0; if (nloc > GS) nloc = GS;
  for (int j = tid; j < nloc; j += 1024) {
    offs[br * N + node0 + j] = (int)rbase + excl[j];
    counts[br * N + node0 + j] = hist[j];
  }
  __syncthreads();
  for (int i = tid; i < rcnt; i += 1024) {
    int pk = stg[i];
    int pos = atomicAdd(&excl[pk >> 17], 1);
    pairs[rbase + pos] = pk & 0x1FFFF;
  }
}

// ---------------- mix kernel: agg(branch A) blocks interleaved with gemm(branch B) blocks ----------------
// Role by exact fractional mapping: block b is gemm iff floor((b+1)*nGemm/nTot) >
// floor(b*nGemm/nTot); gemm_id = floor(b*nGemm/nTot), agg_id = b - gemm_id.
// Agg role: R15 col-half-phased gather (no LDS). Gemm role: R15 BM=64/256thr tile.
// Memory-bound agg + VALU-bound gemm co-resident on every CU -> pipe overlap.

template <int CA, int COUT>
__global__ __launch_bounds__(256, 2) void mix_kernel(
    const float* __restrict__ hA, const int* __restrict__ offsA,
    const int* __restrict__ cntsA, const int* __restrict__ csr,
    const float* __restrict__ gamA, const float* __restrict__ betA,
    float* __restrict__ outA,
    const float* __restrict__ XB, const float* __restrict__ WB,
    const float* __restrict__ biasB, float* __restrict__ YB,
    int n, int nGemm, int nTot) {
  __shared__ float xs[64][128];
  long long b = blockIdx.x;
  int gBefore = (int)((b * nGemm) / nTot);
  int gAfter = (int)(((b + 1) * nGemm) / nTot);
  int tid = threadIdx.x;
  if (gAfter > gBefore) {
    // ---- gemm role: block gBefore ----
    constexpr int CG = COUT / 4;
    constexpr int RG = 256 / CG;
    constexpr int BM = 64;
    constexpr int RPT = BM / RG;
    int block_row = gBefore * BM;
    for (int i = tid; i < BM * 32; i += 256) {
      int r = i >> 5, c4 = i & 31;
      int gr = block_row + r;
      float4 v = make_float4(0.f, 0.f, 0.f, 0.f);
      if (gr < n) v = reinterpret_cast<const float4*>(XB + (size_t)gr * 128)[c4];
      *reinterpret_cast<float4*>(&xs[r][c4 * 4]) = v;
    }
    __syncthreads();
    int c0 = (tid % CG) * 4;
    int r0 = (tid / CG) * RPT;
    float acc[RPT][4] = {};
    #pragma unroll 2
    for (int k = 0; k < 128; k += 4) {
      float4 w0 = *reinterpret_cast<const float4*>(&WB[(k + 0) * COUT + c0]);
      float4 w1 = *reinterpret_cast<const float4*>(&WB[(k + 1) * COUT + c0]);
      float4 w2 = *reinterpret_cast<const float4*>(&WB[(k + 2) * COUT + c0]);
      float4 w3 = *reinterpret_cast<const float4*>(&WB[(k + 3) * COUT + c0]);
      #pragma unroll
      for (int i = 0; i < RPT; ++i) {
        float4 x = *reinterpret_cast<const float4*>(&xs[r0 + i][k]);
        acc[i][0] = fmaf(x.x, w0.x, acc[i][0]);
        acc[i][1] = fmaf(x.x, w0.y, acc[i][1]);
        acc[i][2] = fmaf(x.x, w0.z, acc[i][2]);
        acc[i][3] = fmaf(x.x, w0.w, acc[i][3]);
        acc[i][0] = fmaf(x.y, w1.x, acc[i][0]);
        acc[i][1] = fmaf(x.y, w1.y, acc[i][1]);
        acc[i][2] = fmaf(x.y, w1.z, acc[i][2]);
        acc[i][3] = fmaf(x.y, w1.w, acc[i][3]);
        acc[i][0] = fmaf(x.z, w2.x, acc[i][0]);
        acc[i][1] = fmaf(x.z, w2.y, acc[i][1]);
        acc[i][2] = fmaf(x.z, w2.z, acc[i][2]);
        acc[i][3] = fmaf(x.z, w2.w, acc[i][3]);
        acc[i][0] = fmaf(x.w, w3.x, acc[i][0]);
        acc[i][1] = fmaf(x.w, w3.y, acc[i][1]);
        acc[i][2] = fmaf(x.w, w3.z, acc[i][2]);
        acc[i][3] = fmaf(x.w, w3.w, acc[i][3]);
      }
    }
    float4 bv = *reinterpret_cast<const float4*>(&biasB[c0]);
    #pragma unroll
    for (int i = 0; i < RPT; ++i) {
      int gr = block_row + r0 + i;
      if (gr < n) {
        float4 o;
        o.x = acc[i][0] + bv.x; o.y = acc[i][1] + bv.y;
        o.z = acc[i][2] + bv.z; o.w = acc[i][3] + bv.w;
        *reinterpret_cast<float4*>(&YB[(size_t)gr * COUT + c0]) = o;
      }
    }
  } else {
    // ---- agg role: block (b - gBefore) ----
    int aid = (int)b - gBefore;
    int nb4 = (n + 3) >> 2;
    int ch = aid / nb4;          // col half phase (0 for CA=64)
    int nblk = aid - ch * nb4;
    int node = nblk * 4 + (tid >> 6);
    if (node >= n) return;
    node = __builtin_amdgcn_readfirstlane(node);
    int lane = tid & 63;
    int half = lane >> 5;
    int l5 = lane & 31;
    const float* hh = hA + ch * 64;
    int beg = offsA[node], cnt = cntsA[node];
    const int* lp = csr + beg;
    float a0 = 0.f, a1 = 0.f;
    for (int base = 0; base < cnt; base += 64) {
      int rem = cnt - base;
      int m = rem < 64 ? rem : 64;
      int idx = lp[base + (lane < m ? lane : m - 1)];
      int mfull = m & ~15;
      int j = 0;
      for (; j < mfull; j += 16) {
        float2 v[8];
        #pragma unroll
        for (int u = 0; u < 8; ++u) {
          int s = __shfl(idx, j + 2 * u + half);
          v[u] = *reinterpret_cast<const float2*>(hh + (size_t)s * CA + l5 * 2);
        }
        #pragma unroll
        for (int u = 0; u < 8; ++u) { a0 += v[u].x; a1 += v[u].y; }
      }
      if (j < m) {
        float2 v[8];
        #pragma unroll
        for (int u = 0; u < 8; ++u) {
          int ed = j + 2 * u + half;
          int s = __shfl(idx, ed < m ? ed : m - 1);
          v[u] = *reinterpret_cast<const float2*>(hh + (size_t)s * CA + l5 * 2);
        }
        #pragma unroll
        for (int u = 0; u < 8; ++u) {
          bool ok = (j + 2 * u + half) < m;
          a0 += ok ? v[u].x : 0.f;
          a1 += ok ? v[u].y : 0.f;
        }
      }
    }
    a0 += __shfl_xor(a0, 32);
    a1 += __shfl_xor(a1, 32);
    const float inv = 1.0f / sqrtf(1.0f + 1.0e-3f);
    if (half == 0) {
      float2 g = reinterpret_cast<const float2*>(gamA + ch * 64)[l5];
      float2 be = reinterpret_cast<const float2*>(betA + ch * 64)[l5];
      float2 o;
      o.x = fmaxf(fmaf(a0, g.x * inv, be.x), 0.f);
      o.y = fmaxf(fmaf(a1, g.y * inv, be.y), 0.f);
      *reinterpret_cast<float2*>(outA + (size_t)node * CA + ch * 64 + l5 * 2) = o;
    }
  }
}

// ---------------- Segment mean pool, both branches ----------------

__global__ __launch_bounds__(1024) void pool2_kernel(
    const float* __restrict__ h0, const float* __restrict__ h1,
    const int* __restrict__ seg0, const int* __restrict__ seg1,
    float* __restrict__ p, int n) {
  const float* h = blockIdx.y ? h1 : h0;
  const int* seg = blockIdx.y ? seg1 : seg0;
  float* pb = p + blockIdx.y * 64 * 64;
  int g = blockIdx.x;
  int lo, hi;
  { int l = 0, r = n; while (l < r) { int m = (l + r) >> 1; if (seg[m] < g) l = m + 1; else r = m; } lo = l; }
  { int l = 0, r = n; while (l < r) { int m = (l + r) >> 1; if (seg[m] < g + 1) l = m + 1; else r = m; } hi = l; }
  int c = threadIdx.x & 63;
  int sub = threadIdx.x >> 6;
  float acc = 0.f;
  for (int i = lo + sub; i < hi; i += 16) acc += h[(size_t)i * 64 + c];
  __shared__ float red[16][64];
  red[sub][c] = acc;
  __syncthreads();
  if (sub == 0) {
    float s = 0.f;
    #pragma unroll
    for (int k = 0; k < 16; ++k) s += red[k][c];
    float cnt = (float)(hi - lo);
    pb[g * 64 + c] = s / fmaxf(cnt, 1.0f);
  }
}

// ---------------- Head ----------------

__global__ __launch_bounds__(512) void head_kernel(const float* __restrict__ p,
                                                   const float* __restrict__ Wd,
                                                   const float* __restrict__ bd,
                                                   const float* __restrict__ Wo,
                                                   const float* __restrict__ bo,
                                                   float* __restrict__ out) {
  __shared__ float cur[64][128];
  __shared__ float nxt[64][128];
  int tid = threadIdx.x;
  const float* p1 = p;
  const float* p2 = p + 64 * 64;
  for (int i = tid; i < 64 * 128; i += 512) {
    int r = i >> 7, c = i & 127;
    cur[r][c] = (c < 64) ? p1[r * 64 + c] : p2[r * 64 + (c - 64)];
  }
  __syncthreads();
  int c0 = (tid & 31) * 4;
  int r0 = (tid >> 5) * 4;
  for (int layer = 0; layer < 2; ++layer) {
    float acc[4][4] = {};
    #pragma unroll 4
    for (int k = 0; k < 128; ++k) {
      float4 w = *reinterpret_cast<const float4*>(&Wd[k * 128 + c0]);
      #pragma unroll
      for (int i = 0; i < 4; ++i) {
        float x = cur[r0 + i][k];
        acc[i][0] = fmaf(x, w.x, acc[i][0]);
        acc[i][1] = fmaf(x, w.y, acc[i][1]);
        acc[i][2] = fmaf(x, w.z, acc[i][2]);
        acc[i][3] = fmaf(x, w.w, acc[i][3]);
      }
    }
    float4 bv = *reinterpret_cast<const float4*>(&bd[c0]);
    __syncthreads();
    #pragma unroll
    for (int i = 0; i < 4; ++i) {
      float4 o;
      o.x = fmaxf(acc[i][0] + bv.x, 0.f);
      o.y = fmaxf(acc[i][1] + bv.y, 0.f);
      o.z = fmaxf(acc[i][2] + bv.z, 0.f);
      o.w = fmaxf(acc[i][3] + bv.w, 0.f);
      *reinterpret_cast<float4*>(&nxt[r0 + i][c0]) = o;
    }
    __syncthreads();
    for (int i = tid; i < 64 * 128; i += 512) (&cur[0][0])[i] = (&nxt[0][0])[i];
    __syncthreads();
  }
  int wv = tid >> 6, lane = tid & 63;
  for (int r = wv; r < 64; r += 8) {
    float v = cur[r][lane] * Wo[lane] + cur[r][64 + lane] * Wo[64 + lane];
    #pragma unroll
    for (int off = 32; off; off >>= 1) v += __shfl_down(v, off);
    if (lane == 0) out[r] = 1.0f / (1.0f + expf(-(v + bo[0])));
  }
}

// ---------------- launch ----------------

extern "C" void kernel_launch(void* const* d_in, const int* in_sizes, int n_in,
                              void* d_out, int out_size, void* d_ws, size_t ws_size,
                              hipStream_t stream) {
  const float* x1  = (const float*)d_in[0];
  const float* x2  = (const float*)d_in[1];
  const int* e1    = (const int*)d_in[2];
  const int* e2    = (const int*)d_in[3];
  const int* seg1  = (const int*)d_in[4];
  const int* seg2  = (const int*)d_in[5];
  const float* W1a = (const float*)d_in[6];  const float* b1a = (const float*)d_in[7];
  const float* g1a = (const float*)d_in[8];  const float* be1a = (const float*)d_in[9];
  const float* W1b = (const float*)d_in[10]; const float* b1b = (const float*)d_in[11];
  const float* g1b = (const float*)d_in[12]; const float* be1b = (const float*)d_in[13];
  const float* W2a = (const float*)d_in[14]; const float* b2a = (const float*)d_in[15];
  const float* g2a = (const float*)d_in[16]; const float* be2a = (const float*)d_in[17];
  const float* W2b = (const float*)d_in[18]; const float* b2b = (const float*)d_in[19];
  const float* g2b = (const float*)d_in[20]; const float* be2b = (const float*)d_in[21];
  const float* Wd  = (const float*)d_in[22]; const float* bd  = (const float*)d_in[23];
  const float* Wo  = (const float*)d_in[24]; const float* bo  = (const float*)d_in[25];
  float* out = (float*)d_out;

  const int N = in_sizes[0] / 128;
  const int E = in_sizes[2] / 2;
  const int G1 = (N + GS - 1) >> GSH;
  const int G  = 2 * G1;
  const int nb4 = (N + 3) / 4;      // agg node blocks per col-half
  const int GB  = (N + 63) / 64;    // gemm blocks per branch

  char* ws = (char*)d_ws;
  size_t off = 0;
  auto alloc = [&](size_t bytes) -> void* {
    void* ptr = ws + off;
    off += (bytes + 255) & ~(size_t)255;
    return ptr;
  };
  float* h0   = (float*)alloc((size_t)N * 128 * sizeof(float));
  float* h1   = (float*)alloc((size_t)N * 128 * sizeof(float));
  float* ag0  = (float*)alloc((size_t)N * 128 * sizeof(float));
  float* ag1  = (float*)alloc((size_t)N * 128 * sizeof(float));
  int* pairs  = (int*)alloc((size_t)G * SCAP * sizeof(int));
  int* offs   = (int*)alloc((size_t)(2 * N) * sizeof(int));
  int* counts = (int*)alloc((size_t)(2 * N) * sizeof(int));
  int* gcur   = (int*)alloc((size_t)(G + 8) * sizeof(int));
  float* pbuf = (float*)alloc(2 * 64 * 64 * sizeof(float));
  (void)ws_size; (void)n_in; (void)out_size;

  // ---- CSR build ----
  hipMemsetAsync(gcur, 0, (size_t)(G + 8) * sizeof(int), stream);
  {
    dim3 gb((E + 4095) / 4096, 2);
    bin_kernel<<<gb, 1024, 0, stream>>>(e1, e1 + E, e2, e2 + E, gcur, pairs, E, G1);
    dim3 gr(G1, 2);
    refine_kernel<<<gr, 1024, 0, stream>>>(gcur, pairs, offs, counts, N, G1);
  }

  // ---- branch-pipelined schedule: agg(A) interleaved with gemm(B) per dispatch ----
  // K1: gemm128 br0 alone
  mix_kernel<128, 128><<<GB, 256, 0, stream>>>(
      h0, offs, counts, pairs, g1a, be1a, ag0,
      x1, W1a, b1a, h0, N, GB, GB);
  // K2: agg128 br0 || gemm128 br1
  {
    int nTot = nb4 * 2 + GB;
    mix_kernel<128, 128><<<nTot, 256, 0, stream>>>(
        h0, offs, counts, pairs, g1a, be1a, ag0,
        x2, W2a, b2a, h1, N, GB, nTot);
  }
  // K3: agg128 br1 || gemm64 br0
  {
    int nTot = nb4 * 2 + GB;
    mix_kernel<128, 64><<<nTot, 256, 0, stream>>>(
        h1, offs + N, counts + N, pairs, g2a, be2a, ag1,
        ag0, W1b, b1b, h0, N, GB, nTot);
  }
  // K4: agg64 br0 || gemm64 br1
  {
    int nTot = nb4 + GB;
    mix_kernel<64, 64><<<nTot, 256, 0, stream>>>(
        h0, offs, counts, pairs, g1b, be1b, ag0,
        ag1, W2b, b2b, h1, N, GB, nTot);
  }
  // K5: agg64 br1 alone (nGemm = 0)
  mix_kernel<64, 64><<<nb4, 256, 0, stream>>>(
      h1, offs + N, counts + N, pairs, g2b, be2b, ag1,
      x1, W1a, b1a, h0, N, 0, nb4);

  // pool + head
  {
    dim3 gp(64, 2);
    pool2_kernel<<<gp, 1024, 0, stream>>>(ag0, ag1, seg1, seg2, pbuf, N);
  }
  head_kernel<<<1, 512, 0, stream>>>(pbuf, Wd, bd, Wo, bo, out);
}

// Round 18
// 373.585 us; speedup vs baseline: 1.1756x; 1.1403x over previous
//
#include <hip/hip_runtime.h>
#include <math.h>

#define GS    512   // nodes per group
#define GSH   9
#define NGMAX 128   // max groups per branch (G1=98 for N=50000)
#define FCAP  48    // LDS FIFO capacity per group per round
#define SCAP  10240 // group region capacity

// ---------------- pass 1: bin edges into 512-node groups ----------------

__global__ __launch_bounds__(1024) void bin_kernel(
    const int* __restrict__ s1, const int* __restrict__ d1,
    const int* __restrict__ s2, const int* __restrict__ d2,
    int* __restrict__ gcur, int* __restrict__ pairs, int E, int G1) {
  __shared__ int fifo[NGMAX][FCAP];
  __shared__ int fcnt[NGMAX];
  __shared__ int fbase[NGMAX];
  __shared__ int fpre[NGMAX + 1];
  const int* src = blockIdx.y ? s2 : s1;
  const int* dst = blockIdx.y ? d2 : d1;
  int gboff = blockIdx.y * G1;
  int tid = threadIdx.x;
  if (tid < NGMAX) fcnt[tid] = 0;
  __syncthreads();
  int e0 = blockIdx.x * 4096;
  for (int r = 0; r < 4; ++r) {
    int e = e0 + r * 1024 + tid;
    if (e < E) {
      int s = src[e], d = dst[e];
      int g = d >> GSH;
      int pk = s | ((d & (GS - 1)) << 17);
      int pos = atomicAdd(&fcnt[g], 1);
      if (pos < FCAP) fifo[g][pos] = pk;
      else {
        int gp = atomicAdd(&gcur[gboff + g], 1);
        pairs[(size_t)(gboff + g) * SCAP + gp] = pk;
      }
    }
    __syncthreads();
    if (tid < G1) {
      int c = fcnt[tid];
      if (c > FCAP) c = FCAP;
      fcnt[tid] = c;
      fbase[tid] = (c > 0) ? atomicAdd(&gcur[gboff + tid], c) : 0;
    }
    __syncthreads();
    if (tid == 0) {
      int acc = 0;
      for (int i = 0; i < G1; ++i) { fpre[i] = acc; acc += fcnt[i]; }
      fpre[G1] = acc;
    }
    __syncthreads();
    int T = fpre[G1];
    for (int t = tid; t < T; t += 1024) {
      int lo = 0, hi = G1;
      while (hi - lo > 1) { int mid = (lo + hi) >> 1; if (fpre[mid] <= t) lo = mid; else hi = mid; }
      int idx = t - fpre[lo];
      pairs[(size_t)(gboff + lo) * SCAP + fbase[lo] + idx] = fifo[lo][idx];
    }
    __syncthreads();
    if (tid < NGMAX) fcnt[tid] = 0;
    __syncthreads();
  }
}

// ---------------- pass 2: per-group node CSR, in-place ----------------

__global__ __launch_bounds__(1024) void refine_kernel(
    const int* __restrict__ gcur, int* __restrict__ pairs,
    int* __restrict__ offs, int* __restrict__ counts, int N, int G1) {
  __shared__ int stg[SCAP];
  __shared__ int hist[GS];
  __shared__ int excl[GS];
  __shared__ int wtot[8];
  int gl = blockIdx.x, br = blockIdx.y;
  int g = br * G1 + gl;
  size_t rbase = (size_t)g * SCAP;
  int rcnt = gcur[g];
  if (rcnt > SCAP) rcnt = SCAP;
  int tid = threadIdx.x;
  if (tid < GS) hist[tid] = 0;
  __syncthreads();
  for (int i = tid; i < rcnt; i += 1024) {
    int pk = pairs[rbase + i];
    stg[i] = pk;
    atomicAdd(&hist[pk >> 17], 1);
  }
  __syncthreads();
  if (tid < GS) {
    int lane = tid & 63, wv = tid >> 6;
    int v = hist[tid];
    int inc = v;
    #pragma unroll
    for (int off = 1; off < 64; off <<= 1) {
      int t = __shfl_up(inc, off);
      if (lane >= off) inc += t;
    }
    excl[tid] = inc - v;
    if (lane == 63) wtot[wv] = inc;
  }
  __syncthreads();
  if (tid == 0) {
    int a = 0;
    #pragma unroll
    for (int w = 0; w < 8; ++w) { int t = wtot[w]; wtot[w] = a; a += t; }
  }
  __syncthreads();
  if (tid < GS) excl[tid] += wtot[tid >> 6];
  __syncthreads();
  int node0 = gl * GS;
  int nloc = N - node0; if (nloc > GS) nloc = GS;
  for (int j = tid; j < nloc; j += 1024) {
    offs[br * N + node0 + j] = (int)rbase + excl[j];
    counts[br * N + node0 + j] = hist[j];
  }
  __syncthreads();
  for (int i = tid; i < rcnt; i += 1024) {
    int pk = stg[i];
    int pos = atomicAdd(&excl[pk >> 17], 1);
    pairs[rbase + pos] = pk & 0x1FFFF;
  }
}

// ---------------- GEMM both branches (R15 config, unpadded xs 32KB) ----------------

template <int COUT>
__global__ __launch_bounds__(256, 2) void gemm2_kernel(
    const float* __restrict__ X0, const float* __restrict__ X1,
    const float* __restrict__ W0, const float* __restrict__ W1,
    const float* __restrict__ bias0, const float* __restrict__ bias1,
    float* __restrict__ Y0, float* __restrict__ Y1, int nrows) {
  constexpr int CG = COUT / 4;
  constexpr int RG = 256 / CG;
  constexpr int BM = 64;
  constexpr int RPT = BM / RG;
  const float* X = blockIdx.y ? X1 : X0;
  const float* W = blockIdx.y ? W1 : W0;
  const float* bias = blockIdx.y ? bias1 : bias0;
  float* Y = blockIdx.y ? Y1 : Y0;
  __shared__ float xs[BM][128];
  int tid = threadIdx.x;
  int block_row = blockIdx.x * BM;
  for (int i = tid; i < BM * 32; i += 256) {
    int r = i >> 5, c4 = i & 31;
    int gr = block_row + r;
    float4 v = make_float4(0.f, 0.f, 0.f, 0.f);
    if (gr < nrows) v = reinterpret_cast<const float4*>(X + (size_t)gr * 128)[c4];
    *reinterpret_cast<float4*>(&xs[r][c4 * 4]) = v;
  }
  __syncthreads();
  int c0 = (tid % CG) * 4;
  int r0 = (tid / CG) * RPT;
  float acc[RPT][4] = {};
  #pragma unroll 2
  for (int k = 0; k < 128; k += 4) {
    float4 w0 = *reinterpret_cast<const float4*>(&W[(k + 0) * COUT + c0]);
    float4 w1 = *reinterpret_cast<const float4*>(&W[(k + 1) * COUT + c0]);
    float4 w2 = *reinterpret_cast<const float4*>(&W[(k + 2) * COUT + c0]);
    float4 w3 = *reinterpret_cast<const float4*>(&W[(k + 3) * COUT + c0]);
    #pragma unroll
    for (int i = 0; i < RPT; ++i) {
      float4 x = *reinterpret_cast<const float4*>(&xs[r0 + i][k]);
      acc[i][0] = fmaf(x.x, w0.x, acc[i][0]);
      acc[i][1] = fmaf(x.x, w0.y, acc[i][1]);
      acc[i][2] = fmaf(x.x, w0.z, acc[i][2]);
      acc[i][3] = fmaf(x.x, w0.w, acc[i][3]);
      acc[i][0] = fmaf(x.y, w1.x, acc[i][0]);
      acc[i][1] = fmaf(x.y, w1.y, acc[i][1]);
      acc[i][2] = fmaf(x.y, w1.z, acc[i][2]);
      acc[i][3] = fmaf(x.y, w1.w, acc[i][3]);
      acc[i][0] = fmaf(x.z, w2.x, acc[i][0]);
      acc[i][1] = fmaf(x.z, w2.y, acc[i][1]);
      acc[i][2] = fmaf(x.z, w2.z, acc[i][2]);
      acc[i][3] = fmaf(x.z, w2.w, acc[i][3]);
      acc[i][0] = fmaf(x.w, w3.x, acc[i][0]);
      acc[i][1] = fmaf(x.w, w3.y, acc[i][1]);
      acc[i][2] = fmaf(x.w, w3.z, acc[i][2]);
      acc[i][3] = fmaf(x.w, w3.w, acc[i][3]);
    }
  }
  float4 bv = *reinterpret_cast<const float4*>(&bias[c0]);
  #pragma unroll
  for (int i = 0; i < RPT; ++i) {
    int gr = block_row + r0 + i;
    if (gr < nrows) {
      float4 o;
      o.x = acc[i][0] + bv.x; o.y = acc[i][1] + bv.y;
      o.z = acc[i][2] + bv.z; o.w = acc[i][3] + bv.w;
      *reinterpret_cast<float4*>(&Y[(size_t)gr * COUT + c0]) = o;
    }
  }
}

// ---------------- agg, 32-col slice phases (window 6.4MB ~ L2-sized) ----------------
// C=128: blockIdx.y = br*4 + sl (8 phases). C=64: y = br*2 + sl (4 phases).
// Wave per node; per edge: 8 lanes x float4 = 32 cols -> 8 edges per wave-load,
// 4-deep unroll (32 edge slots in flight). Cross-group shfl_xor reduce at end.

template <int C>
__global__ __launch_bounds__(256) void agg_sl_kernel(
    const float* __restrict__ h0, const float* __restrict__ h1,
    const int* __restrict__ offs, const int* __restrict__ counts,
    const int* __restrict__ csr,
    const float* __restrict__ ga0, const float* __restrict__ be0,
    const float* __restrict__ ga1, const float* __restrict__ be1,
    float* __restrict__ o0, float* __restrict__ o1, int n) {
  constexpr int NSL = C / 32;
  int node = blockIdx.x * 4 + (threadIdx.x >> 6);
  if (node >= n) return;
  node = __builtin_amdgcn_readfirstlane(node);
  int br = blockIdx.y / NSL, sl = blockIdx.y % NSL;
  const float* h = br ? h1 : h0;
  const float* gamma = br ? ga1 : ga0;
  const float* beta = br ? be1 : be0;
  float* out = br ? o1 : o0;
  int lane = threadIdx.x & 63;
  int grp = lane >> 3;      // edge slot 0..7
  int c4 = lane & 7;        // col quad within 32-col slice
  const float* hp = h + sl * 32 + c4 * 4;
  int beg = offs[br * n + node], cnt = counts[br * n + node];
  const int* lp = csr + beg;
  float4 a = make_float4(0.f, 0.f, 0.f, 0.f);
  for (int base = 0; base < cnt; base += 64) {
    int rem = cnt - base;
    int m = rem < 64 ? rem : 64;
    int idx = lp[base + (lane < m ? lane : m - 1)];
    int mfull = m & ~31;
    int j = 0;
    for (; j < mfull; j += 32) {   // 32 edges per iter, 4 float4 loads in flight
      float4 v[4];
      #pragma unroll
      for (int u = 0; u < 4; ++u) {
        int s = __shfl(idx, j + u * 8 + grp);
        v[u] = *reinterpret_cast<const float4*>(hp + (size_t)s * C);
      }
      #pragma unroll
      for (int u = 0; u < 4; ++u) { a.x += v[u].x; a.y += v[u].y; a.z += v[u].z; a.w += v[u].w; }
    }
    if (j < m) {   // masked tail (<32 edges)
      float4 v[4];
      #pragma unroll
      for (int u = 0; u < 4; ++u) {
        int e = j + u * 8 + grp;
        int s = __shfl(idx, e < m ? e : m - 1);
        v[u] = *reinterpret_cast<const float4*>(hp + (size_t)s * C);
      }
      #pragma unroll
      for (int u = 0; u < 4; ++u) {
        bool ok = (j + u * 8 + grp) < m;
        a.x += ok ? v[u].x : 0.f;
        a.y += ok ? v[u].y : 0.f;
        a.z += ok ? v[u].z : 0.f;
        a.w += ok ? v[u].w : 0.f;
      }
    }
  }
  // reduce across the 8 edge groups (lanes with same c4)
  #pragma unroll
  for (int off = 8; off < 64; off <<= 1) {
    a.x += __shfl_xor(a.x, off);
    a.y += __shfl_xor(a.y, off);
    a.z += __shfl_xor(a.z, off);
    a.w += __shfl_xor(a.w, off);
  }
  if (grp == 0) {
    const float inv = 1.0f / sqrtf(1.0f + 1.0e-3f);
    float4 gv = *reinterpret_cast<const float4*>(gamma + sl * 32 + c4 * 4);
    float4 bv = *reinterpret_cast<const float4*>(beta + sl * 32 + c4 * 4);
    float4 o;
    o.x = fmaxf(fmaf(a.x, gv.x * inv, bv.x), 0.f);
    o.y = fmaxf(fmaf(a.y, gv.y * inv, bv.y), 0.f);
    o.z = fmaxf(fmaf(a.z, gv.z * inv, bv.z), 0.f);
    o.w = fmaxf(fmaf(a.w, gv.w * inv, bv.w), 0.f);
    *reinterpret_cast<float4*>(out + (size_t)node * C + sl * 32 + c4 * 4) = o;
  }
}

// ---------------- Segment mean pool, both branches ----------------

__global__ __launch_bounds__(1024) void pool2_kernel(
    const float* __restrict__ h0, const float* __restrict__ h1,
    const int* __restrict__ seg0, const int* __restrict__ seg1,
    float* __restrict__ p, int n) {
  const float* h = blockIdx.y ? h1 : h0;
  const int* seg = blockIdx.y ? seg1 : seg0;
  float* pb = p + blockIdx.y * 64 * 64;
  int g = blockIdx.x;
  int lo, hi;
  { int l = 0, r = n; while (l < r) { int m = (l + r) >> 1; if (seg[m] < g) l = m + 1; else r = m; } lo = l; }
  { int l = 0, r = n; while (l < r) { int m = (l + r) >> 1; if (seg[m] < g + 1) l = m + 1; else r = m; } hi = l; }
  int c = threadIdx.x & 63;
  int sub = threadIdx.x >> 6;
  float acc = 0.f;
  for (int i = lo + sub; i < hi; i += 16) acc += h[(size_t)i * 64 + c];
  __shared__ float red[16][64];
  red[sub][c] = acc;
  __syncthreads();
  if (sub == 0) {
    float s = 0.f;
    #pragma unroll
    for (int k = 0; k < 16; ++k) s += red[k][c];
    float cnt = (float)(hi - lo);
    pb[g * 64 + c] = s / fmaxf(cnt, 1.0f);
  }
}

// ---------------- Head ----------------

__global__ __launch_bounds__(512) void head_kernel(const float* __restrict__ p,
                                                   const float* __restrict__ Wd,
                                                   const float* __restrict__ bd,
                                                   const float* __restrict__ Wo,
                                                   const float* __restrict__ bo,
                                                   float* __restrict__ out) {
  __shared__ float cur[64][128];
  __shared__ float nxt[64][128];
  int tid = threadIdx.x;
  const float* p1 = p;
  const float* p2 = p + 64 * 64;
  for (int i = tid; i < 64 * 128; i += 512) {
    int r = i >> 7, c = i & 127;
    cur[r][c] = (c < 64) ? p1[r * 64 + c] : p2[r * 64 + (c - 64)];
  }
  __syncthreads();
  int c0 = (tid & 31) * 4;
  int r0 = (tid >> 5) * 4;
  for (int layer = 0; layer < 2; ++layer) {
    float acc[4][4] = {};
    #pragma unroll 4
    for (int k = 0; k < 128; ++k) {
      float4 w = *reinterpret_cast<const float4*>(&Wd[k * 128 + c0]);
      #pragma unroll
      for (int i = 0; i < 4; ++i) {
        float x = cur[r0 + i][k];
        acc[i][0] = fmaf(x, w.x, acc[i][0]);
        acc[i][1] = fmaf(x, w.y, acc[i][1]);
        acc[i][2] = fmaf(x, w.z, acc[i][2]);
        acc[i][3] = fmaf(x, w.w, acc[i][3]);
      }
    }
    float4 bv = *reinterpret_cast<const float4*>(&bd[c0]);
    __syncthreads();
    #pragma unroll
    for (int i = 0; i < 4; ++i) {
      float4 o;
      o.x = fmaxf(acc[i][0] + bv.x, 0.f);
      o.y = fmaxf(acc[i][1] + bv.y, 0.f);
      o.z = fmaxf(acc[i][2] + bv.z, 0.f);
      o.w = fmaxf(acc[i][3] + bv.w, 0.f);
      *reinterpret_cast<float4*>(&nxt[r0 + i][c0]) = o;
    }
    __syncthreads();
    for (int i = tid; i < 64 * 128; i += 512) (&cur[0][0])[i] = (&nxt[0][0])[i];
    __syncthreads();
  }
  int wv = tid >> 6, lane = tid & 63;
  for (int r = wv; r < 64; r += 8) {
    float v = cur[r][lane] * Wo[lane] + cur[r][64 + lane] * Wo[64 + lane];
    #pragma unroll
    for (int off = 32; off; off >>= 1) v += __shfl_down(v, off);
    if (lane == 0) out[r] = 1.0f / (1.0f + expf(-(v + bo[0])));
  }
}

// ---------------- launch ----------------

extern "C" void kernel_launch(void* const* d_in, const int* in_sizes, int n_in,
                              void* d_out, int out_size, void* d_ws, size_t ws_size,
                              hipStream_t stream) {
  const float* x1  = (const float*)d_in[0];
  const float* x2  = (const float*)d_in[1];
  const int* e1    = (const int*)d_in[2];
  const int* e2    = (const int*)d_in[3];
  const int* seg1  = (const int*)d_in[4];
  const int* seg2  = (const int*)d_in[5];
  const float* W1a = (const float*)d_in[6];  const float* b1a = (const float*)d_in[7];
  const float* g1a = (const float*)d_in[8];  const float* be1a = (const float*)d_in[9];
  const float* W1b = (const float*)d_in[10]; const float* b1b = (const float*)d_in[11];
  const float* g1b = (const float*)d_in[12]; const float* be1b = (const float*)d_in[13];
  const float* W2a = (const float*)d_in[14]; const float* b2a = (const float*)d_in[15];
  const float* g2a = (const float*)d_in[16]; const float* be2a = (const float*)d_in[17];
  const float* W2b = (const float*)d_in[18]; const float* b2b = (const float*)d_in[19];
  const float* g2b = (const float*)d_in[20]; const float* be2b = (const float*)d_in[21];
  const float* Wd  = (const float*)d_in[22]; const float* bd  = (const float*)d_in[23];
  const float* Wo  = (const float*)d_in[24]; const float* bo  = (const float*)d_in[25];
  float* out = (float*)d_out;

  const int N = in_sizes[0] / 128;
  const int E = in_sizes[2] / 2;
  const int G1 = (N + GS - 1) >> GSH;
  const int G  = 2 * G1;

  char* ws = (char*)d_ws;
  size_t off = 0;
  auto alloc = [&](size_t bytes) -> void* {
    void* ptr = ws + off;
    off += (bytes + 255) & ~(size_t)255;
    return ptr;
  };
  float* h0   = (float*)alloc((size_t)N * 128 * sizeof(float));
  float* h1   = (float*)alloc((size_t)N * 128 * sizeof(float));
  float* ag0  = (float*)alloc((size_t)N * 128 * sizeof(float));
  float* ag1  = (float*)alloc((size_t)N * 128 * sizeof(float));
  int* pairs  = (int*)alloc((size_t)G * SCAP * sizeof(int));
  int* offs   = (int*)alloc((size_t)(2 * N) * sizeof(int));
  int* counts = (int*)alloc((size_t)(2 * N) * sizeof(int));
  int* gcur   = (int*)alloc((size_t)(G + 8) * sizeof(int));
  float* pbuf = (float*)alloc(2 * 64 * 64 * sizeof(float));
  (void)ws_size; (void)n_in; (void)out_size;

  // ---- CSR build ----
  hipMemsetAsync(gcur, 0, (size_t)(G + 8) * sizeof(int), stream);
  {
    dim3 gb((E + 4095) / 4096, 2);
    bin_kernel<<<gb, 1024, 0, stream>>>(e1, e1 + E, e2, e2 + E, gcur, pairs, E, G1);
    dim3 gr(G1, 2);
    refine_kernel<<<gr, 1024, 0, stream>>>(gcur, pairs, offs, counts, N, G1);
  }

  // layer 1
  {
    dim3 gg((N + 63) / 64, 2);
    gemm2_kernel<128><<<gg, 256, 0, stream>>>(x1, x2, W1a, W2a, b1a, b2a, h0, h1, N);
  }
  {
    dim3 ga((N + 3) / 4, 8);   // 2 branches x 4 slices
    agg_sl_kernel<128><<<ga, 256, 0, stream>>>(h0, h1, offs, counts, pairs,
                                               g1a, be1a, g2a, be2a, ag0, ag1, N);
  }
  // layer 2
  {
    dim3 gg((N + 63) / 64, 2);
    gemm2_kernel<64><<<gg, 256, 0, stream>>>(ag0, ag1, W1b, W2b, b1b, b2b, h0, h1, N);
  }
  {
    dim3 ga((N + 3) / 4, 4);   // 2 branches x 2 slices
    agg_sl_kernel<64><<<ga, 256, 0, stream>>>(h0, h1, offs, counts, pairs,
                                              g1b, be1b, g2b, be2b, ag0, ag1, N);
  }
  // pool + head
  {
    dim3 gp(64, 2);
    pool2_kernel<<<gp, 1024, 0, stream>>>(ag0, ag1, seg1, seg2, pbuf, N);
  }
  head_kernel<<<1, 512, 0, stream>>>(pbuf, Wd, bd, Wo, bo, out);
}

// Round 19
// 330.713 us; speedup vs baseline: 1.3279x; 1.1296x over previous
//
#include <hip/hip_runtime.h>
#include <math.h>

#define GS    512   // nodes per group
#define GSH   9
#define NGMAX 128   // max groups per branch (G1=98 for N=50000)
#define FCAP  48    // LDS FIFO capacity per group per round
#define SCAP  10240 // group region capacity

// ---------------- pass 1: bin edges into 512-node groups ----------------

__global__ __launch_bounds__(1024) void bin_kernel(
    const int* __restrict__ s1, const int* __restrict__ d1,
    const int* __restrict__ s2, const int* __restrict__ d2,
    int* __restrict__ gcur, int* __restrict__ pairs, int E, int G1) {
  __shared__ int fifo[NGMAX][FCAP];
  __shared__ int fcnt[NGMAX];
  __shared__ int fbase[NGMAX];
  __shared__ int fpre[NGMAX + 1];
  const int* src = blockIdx.y ? s2 : s1;
  const int* dst = blockIdx.y ? d2 : d1;
  int gboff = blockIdx.y * G1;
  int tid = threadIdx.x;
  if (tid < NGMAX) fcnt[tid] = 0;
  __syncthreads();
  int e0 = blockIdx.x * 4096;
  for (int r = 0; r < 4; ++r) {
    int e = e0 + r * 1024 + tid;
    if (e < E) {
      int s = src[e], d = dst[e];
      int g = d >> GSH;
      int pk = s | ((d & (GS - 1)) << 17);
      int pos = atomicAdd(&fcnt[g], 1);
      if (pos < FCAP) fifo[g][pos] = pk;
      else {
        int gp = atomicAdd(&gcur[gboff + g], 1);
        pairs[(size_t)(gboff + g) * SCAP + gp] = pk;
      }
    }
    __syncthreads();
    if (tid < G1) {
      int c = fcnt[tid];
      if (c > FCAP) c = FCAP;
      fcnt[tid] = c;
      fbase[tid] = (c > 0) ? atomicAdd(&gcur[gboff + tid], c) : 0;
    }
    __syncthreads();
    if (tid == 0) {
      int acc = 0;
      for (int i = 0; i < G1; ++i) { fpre[i] = acc; acc += fcnt[i]; }
      fpre[G1] = acc;
    }
    __syncthreads();
    int T = fpre[G1];
    for (int t = tid; t < T; t += 1024) {
      int lo = 0, hi = G1;
      while (hi - lo > 1) { int mid = (lo + hi) >> 1; if (fpre[mid] <= t) lo = mid; else hi = mid; }
      int idx = t - fpre[lo];
      pairs[(size_t)(gboff + lo) * SCAP + fbase[lo] + idx] = fifo[lo][idx];
    }
    __syncthreads();
    if (tid < NGMAX) fcnt[tid] = 0;
    __syncthreads();
  }
}

// ---------------- pass 2: per-group node CSR, in-place ----------------

__global__ __launch_bounds__(1024) void refine_kernel(
    const int* __restrict__ gcur, int* __restrict__ pairs,
    int* __restrict__ offs, int* __restrict__ counts, int N, int G1) {
  __shared__ int stg[SCAP];
  __shared__ int hist[GS];
  __shared__ int excl[GS];
  __shared__ int wtot[8];
  int gl = blockIdx.x, br = blockIdx.y;
  int g = br * G1 + gl;
  size_t rbase = (size_t)g * SCAP;
  int rcnt = gcur[g];
  if (rcnt > SCAP) rcnt = SCAP;
  int tid = threadIdx.x;
  if (tid < GS) hist[tid] = 0;
  __syncthreads();
  for (int i = tid; i < rcnt; i += 1024) {
    int pk = pairs[rbase + i];
    stg[i] = pk;
    atomicAdd(&hist[pk >> 17], 1);
  }
  __syncthreads();
  if (tid < GS) {
    int lane = tid & 63, wv = tid >> 6;
    int v = hist[tid];
    int inc = v;
    #pragma unroll
    for (int off = 1; off < 64; off <<= 1) {
      int t = __shfl_up(inc, off);
      if (lane >= off) inc += t;
    }
    excl[tid] = inc - v;
    if (lane == 63) wtot[wv] = inc;
  }
  __syncthreads();
  if (tid == 0) {
    int a = 0;
    #pragma unroll
    for (int w = 0; w < 8; ++w) { int t = wtot[w]; wtot[w] = a; a += t; }
  }
  __syncthreads();
  if (tid < GS) excl[tid] += wtot[tid >> 6];
  __syncthreads();
  int node0 = gl * GS;
  int nloc = N - node0; if (nloc > GS) nloc = GS;
  for (int j = tid; j < nloc; j += 1024) {
    offs[br * N + node0 + j] = (int)rbase + excl[j];
    counts[br * N + node0 + j] = hist[j];
  }
  __syncthreads();
  for (int i = tid; i < rcnt; i += 1024) {
    int pk = stg[i];
    int pos = atomicAdd(&excl[pk >> 17], 1);
    pairs[rbase + pos] = pk & 0x1FFFF;
  }
}

// ---------------- GEMM both branches (unpadded xs = 32KB -> 5 blocks/CU) ----------------

template <int COUT>
__global__ __launch_bounds__(256, 2) void gemm2_kernel(
    const float* __restrict__ X0, const float* __restrict__ X1,
    const float* __restrict__ W0, const float* __restrict__ W1,
    const float* __restrict__ bias0, const float* __restrict__ bias1,
    float* __restrict__ Y0, float* __restrict__ Y1, int nrows) {
  constexpr int CG = COUT / 4;
  constexpr int RG = 256 / CG;
  constexpr int BM = 64;
  constexpr int RPT = BM / RG;
  const float* X = blockIdx.y ? X1 : X0;
  const float* W = blockIdx.y ? W1 : W0;
  const float* bias = blockIdx.y ? bias1 : bias0;
  float* Y = blockIdx.y ? Y1 : Y0;
  __shared__ float xs[BM][128];
  int tid = threadIdx.x;
  int block_row = blockIdx.x * BM;
  for (int i = tid; i < BM * 32; i += 256) {
    int r = i >> 5, c4 = i & 31;
    int gr = block_row + r;
    float4 v = make_float4(0.f, 0.f, 0.f, 0.f);
    if (gr < nrows) v = reinterpret_cast<const float4*>(X + (size_t)gr * 128)[c4];
    *reinterpret_cast<float4*>(&xs[r][c4 * 4]) = v;
  }
  __syncthreads();
  int c0 = (tid % CG) * 4;
  int r0 = (tid / CG) * RPT;
  float acc[RPT][4] = {};
  #pragma unroll 2
  for (int k = 0; k < 128; k += 4) {
    float4 w0 = *reinterpret_cast<const float4*>(&W[(k + 0) * COUT + c0]);
    float4 w1 = *reinterpret_cast<const float4*>(&W[(k + 1) * COUT + c0]);
    float4 w2 = *reinterpret_cast<const float4*>(&W[(k + 2) * COUT + c0]);
    float4 w3 = *reinterpret_cast<const float4*>(&W[(k + 3) * COUT + c0]);
    #pragma unroll
    for (int i = 0; i < RPT; ++i) {
      float4 x = *reinterpret_cast<const float4*>(&xs[r0 + i][k]);
      acc[i][0] = fmaf(x.x, w0.x, acc[i][0]);
      acc[i][1] = fmaf(x.x, w0.y, acc[i][1]);
      acc[i][2] = fmaf(x.x, w0.z, acc[i][2]);
      acc[i][3] = fmaf(x.x, w0.w, acc[i][3]);
      acc[i][0] = fmaf(x.y, w1.x, acc[i][0]);
      acc[i][1] = fmaf(x.y, w1.y, acc[i][1]);
      acc[i][2] = fmaf(x.y, w1.z, acc[i][2]);
      acc[i][3] = fmaf(x.y, w1.w, acc[i][3]);
      acc[i][0] = fmaf(x.z, w2.x, acc[i][0]);
      acc[i][1] = fmaf(x.z, w2.y, acc[i][1]);
      acc[i][2] = fmaf(x.z, w2.z, acc[i][2]);
      acc[i][3] = fmaf(x.z, w2.w, acc[i][3]);
      acc[i][0] = fmaf(x.w, w3.x, acc[i][0]);
      acc[i][1] = fmaf(x.w, w3.y, acc[i][1]);
      acc[i][2] = fmaf(x.w, w3.z, acc[i][2]);
      acc[i][3] = fmaf(x.w, w3.w, acc[i][3]);
    }
  }
  float4 bv = *reinterpret_cast<const float4*>(&bias[c0]);
  #pragma unroll
  for (int i = 0; i < RPT; ++i) {
    int gr = block_row + r0 + i;
    if (gr < nrows) {
      float4 o;
      o.x = acc[i][0] + bv.x; o.y = acc[i][1] + bv.y;
      o.z = acc[i][2] + bv.z; o.w = acc[i][3] + bv.w;
      *reinterpret_cast<float4*>(&Y[(size_t)gr * COUT + c0]) = o;
    }
  }
}

// ---------------- agg C=128, both branches + col halves in one dispatch ----------------

__global__ __launch_bounds__(256) void agg128_kernel(
    const float* __restrict__ h0, const float* __restrict__ h1,
    const int* __restrict__ offs, const int* __restrict__ counts,
    const int* __restrict__ csr_src,
    const float* __restrict__ ga0, const float* __restrict__ be0,
    const float* __restrict__ ga1, const float* __restrict__ be1,
    float* __restrict__ o0, float* __restrict__ o1, int n) {
  int node = blockIdx.x * 4 + (threadIdx.x >> 6);
  if (node >= n) return;
  node = __builtin_amdgcn_readfirstlane(node);
  int br = blockIdx.y >> 1, ch = blockIdx.y & 1;
  const float* h = br ? h1 : h0;
  const float* gamma = br ? ga1 : ga0;
  const float* beta = br ? be1 : be0;
  float* out = br ? o1 : o0;
  int lane = threadIdx.x & 63;
  int half = lane >> 5;
  int l5 = lane & 31;
  const float* hh = h + ch * 64;
  int beg = offs[br * n + node], cnt = counts[br * n + node];
  const int* lp = csr_src + beg;
  float a0 = 0.f, a1 = 0.f;
  for (int base = 0; base < cnt; base += 64) {
    int rem = cnt - base;
    int m = rem < 64 ? rem : 64;
    int idx = lp[base + (lane < m ? lane : m - 1)];
    int mfull = m & ~15;
    int j = 0;
    for (; j < mfull; j += 16) {
      float2 v[8];
      #pragma unroll
      for (int u = 0; u < 8; ++u) {
        int s = __shfl(idx, j + 2 * u + half);
        v[u] = *reinterpret_cast<const float2*>(hh + (size_t)s * 128 + l5 * 2);
      }
      #pragma unroll
      for (int u = 0; u < 8; ++u) { a0 += v[u].x; a1 += v[u].y; }
    }
    if (j < m) {
      float2 v[8];
      #pragma unroll
      for (int u = 0; u < 8; ++u) {
        int ed = j + 2 * u + half;
        int s = __shfl(idx, ed < m ? ed : m - 1);
        v[u] = *reinterpret_cast<const float2*>(hh + (size_t)s * 128 + l5 * 2);
      }
      #pragma unroll
      for (int u = 0; u < 8; ++u) {
        bool ok = (j + 2 * u + half) < m;
        a0 += ok ? v[u].x : 0.f;
        a1 += ok ? v[u].y : 0.f;
      }
    }
  }
  a0 += __shfl_xor(a0, 32);
  a1 += __shfl_xor(a1, 32);
  const float inv = 1.0f / sqrtf(1.0f + 1.0e-3f);
  if (half == 0) {
    float2 g = reinterpret_cast<const float2*>(gamma + ch * 64)[l5];
    float2 b = reinterpret_cast<const float2*>(beta + ch * 64)[l5];
    float2 o;
    o.x = fmaxf(fmaf(a0, g.x * inv, b.x), 0.f);
    o.y = fmaxf(fmaf(a1, g.y * inv, b.y), 0.f);
    *reinterpret_cast<float2*>(out + (size_t)node * 128 + ch * 64 + l5 * 2) = o;
  }
}

// ---------------- agg C=64, both branches in one dispatch (blockIdx.y = br) ----------------

__global__ __launch_bounds__(256) void agg64_kernel(
    const float* __restrict__ h0, const float* __restrict__ h1,
    const int* __restrict__ offs, const int* __restrict__ counts,
    const int* __restrict__ csr_src,
    const float* __restrict__ ga0, const float* __restrict__ be0,
    const float* __restrict__ ga1, const float* __restrict__ be1,
    float* __restrict__ o0, float* __restrict__ o1, int n) {
  int node = blockIdx.x * 4 + (threadIdx.x >> 6);
  if (node >= n) return;
  node = __builtin_amdgcn_readfirstlane(node);
  int br = blockIdx.y;
  const float* h = br ? h1 : h0;
  const float* gamma = br ? ga1 : ga0;
  const float* beta = br ? be1 : be0;
  float* out = br ? o1 : o0;
  int lane = threadIdx.x & 63;
  int half = lane >> 5;
  int l5 = lane & 31;
  int beg = offs[br * n + node], cnt = counts[br * n + node];
  const int* lp = csr_src + beg;
  float a0 = 0.f, a1 = 0.f;
  for (int base = 0; base < cnt; base += 64) {
    int rem = cnt - base;
    int m = rem < 64 ? rem : 64;
    int idx = lp[base + (lane < m ? lane : m - 1)];
    int mfull = m & ~15;
    int j = 0;
    for (; j < mfull; j += 16) {
      float2 v[8];
      #pragma unroll
      for (int u = 0; u < 8; ++u) {
        int s = __shfl(idx, j + 2 * u + half);
        v[u] = *reinterpret_cast<const float2*>(h + (size_t)s * 64 + l5 * 2);
      }
      #pragma unroll
      for (int u = 0; u < 8; ++u) { a0 += v[u].x; a1 += v[u].y; }
    }
    if (j < m) {
      float2 v[8];
      #pragma unroll
      for (int u = 0; u < 8; ++u) {
        int ed = j + 2 * u + half;
        int s = __shfl(idx, ed < m ? ed : m - 1);
        v[u] = *reinterpret_cast<const float2*>(h + (size_t)s * 64 + l5 * 2);
      }
      #pragma unroll
      for (int u = 0; u < 8; ++u) {
        bool ok = (j + 2 * u + half) < m;
        a0 += ok ? v[u].x : 0.f;
        a1 += ok ? v[u].y : 0.f;
      }
    }
  }
  a0 += __shfl_xor(a0, 32);
  a1 += __shfl_xor(a1, 32);
  const float inv = 1.0f / sqrtf(1.0f + 1.0e-3f);
  if (half == 0) {
    float2 g = reinterpret_cast<const float2*>(gamma)[l5];
    float2 b = reinterpret_cast<const float2*>(beta)[l5];
    float2 o;
    o.x = fmaxf(fmaf(a0, g.x * inv, b.x), 0.f);
    o.y = fmaxf(fmaf(a1, g.y * inv, b.y), 0.f);
    *reinterpret_cast<float2*>(out + (size_t)node * 64 + l5 * 2) = o;
  }
}

// ---------------- Segment mean pool, both branches ----------------

__global__ __launch_bounds__(1024) void pool2_kernel(
    const float* __restrict__ h0, const float* __restrict__ h1,
    const int* __restrict__ seg0, const int* __restrict__ seg1,
    float* __restrict__ p, int n) {
  const float* h = blockIdx.y ? h1 : h0;
  const int* seg = blockIdx.y ? seg1 : seg0;
  float* pb = p + blockIdx.y * 64 * 64;
  int g = blockIdx.x;
  int lo, hi;
  { int l = 0, r = n; while (l < r) { int m = (l + r) >> 1; if (seg[m] < g) l = m + 1; else r = m; } lo = l; }
  { int l = 0, r = n; while (l < r) { int m = (l + r) >> 1; if (seg[m] < g + 1) l = m + 1; else r = m; } hi = l; }
  int c = threadIdx.x & 63;
  int sub = threadIdx.x >> 6;
  float acc = 0.f;
  for (int i = lo + sub; i < hi; i += 16) acc += h[(size_t)i * 64 + c];
  __shared__ float red[16][64];
  red[sub][c] = acc;
  __syncthreads();
  if (sub == 0) {
    float s = 0.f;
    #pragma unroll
    for (int k = 0; k < 16; ++k) s += red[k][c];
    float cnt = (float)(hi - lo);
    pb[g * 64 + c] = s / fmaxf(cnt, 1.0f);
  }
}

// ---------------- Head ----------------

__global__ __launch_bounds__(512) void head_kernel(const float* __restrict__ p,
                                                   const float* __restrict__ Wd,
                                                   const float* __restrict__ bd,
                                                   const float* __restrict__ Wo,
                                                   const float* __restrict__ bo,
                                                   float* __restrict__ out) {
  __shared__ float cur[64][128];
  __shared__ float nxt[64][128];
  int tid = threadIdx.x;
  const float* p1 = p;
  const float* p2 = p + 64 * 64;
  for (int i = tid; i < 64 * 128; i += 512) {
    int r = i >> 7, c = i & 127;
    cur[r][c] = (c < 64) ? p1[r * 64 + c] : p2[r * 64 + (c - 64)];
  }
  __syncthreads();
  int c0 = (tid & 31) * 4;
  int r0 = (tid >> 5) * 4;
  for (int layer = 0; layer < 2; ++layer) {
    float acc[4][4] = {};
    #pragma unroll 4
    for (int k = 0; k < 128; ++k) {
      float4 w = *reinterpret_cast<const float4*>(&Wd[k * 128 + c0]);
      #pragma unroll
      for (int i = 0; i < 4; ++i) {
        float x = cur[r0 + i][k];
        acc[i][0] = fmaf(x, w.x, acc[i][0]);
        acc[i][1] = fmaf(x, w.y, acc[i][1]);
        acc[i][2] = fmaf(x, w.z, acc[i][2]);
        acc[i][3] = fmaf(x, w.w, acc[i][3]);
      }
    }
    float4 bv = *reinterpret_cast<const float4*>(&bd[c0]);
    __syncthreads();
    #pragma unroll
    for (int i = 0; i < 4; ++i) {
      float4 o;
      o.x = fmaxf(acc[i][0] + bv.x, 0.f);
      o.y = fmaxf(acc[i][1] + bv.y, 0.f);
      o.z = fmaxf(acc[i][2] + bv.z, 0.f);
      o.w = fmaxf(acc[i][3] + bv.w, 0.f);
      *reinterpret_cast<float4*>(&nxt[r0 + i][c0]) = o;
    }
    __syncthreads();
    for (int i = tid; i < 64 * 128; i += 512) (&cur[0][0])[i] = (&nxt[0][0])[i];
    __syncthreads();
  }
  int wv = tid >> 6, lane = tid & 63;
  for (int r = wv; r < 64; r += 8) {
    float v = cur[r][lane] * Wo[lane] + cur[r][64 + lane] * Wo[64 + lane];
    #pragma unroll
    for (int off = 32; off; off >>= 1) v += __shfl_down(v, off);
    if (lane == 0) out[r] = 1.0f / (1.0f + expf(-(v + bo[0])));
  }
}

// ---------------- launch ----------------

extern "C" void kernel_launch(void* const* d_in, const int* in_sizes, int n_in,
                              void* d_out, int out_size, void* d_ws, size_t ws_size,
                              hipStream_t stream) {
  const float* x1  = (const float*)d_in[0];
  const float* x2  = (const float*)d_in[1];
  const int* e1    = (const int*)d_in[2];
  const int* e2    = (const int*)d_in[3];
  const int* seg1  = (const int*)d_in[4];
  const int* seg2  = (const int*)d_in[5];
  const float* W1a = (const float*)d_in[6];  const float* b1a = (const float*)d_in[7];
  const float* g1a = (const float*)d_in[8];  const float* be1a = (const float*)d_in[9];
  const float* W1b = (const float*)d_in[10]; const float* b1b = (const float*)d_in[11];
  const float* g1b = (const float*)d_in[12]; const float* be1b = (const float*)d_in[13];
  const float* W2a = (const float*)d_in[14]; const float* b2a = (const float*)d_in[15];
  const float* g2a = (const float*)d_in[16]; const float* be2a = (const float*)d_in[17];
  const float* W2b = (const float*)d_in[18]; const float* b2b = (const float*)d_in[19];
  const float* g2b = (const float*)d_in[20]; const float* be2b = (const float*)d_in[21];
  const float* Wd  = (const float*)d_in[22]; const float* bd  = (const float*)d_in[23];
  const float* Wo  = (const float*)d_in[24]; const float* bo  = (const float*)d_in[25];
  float* out = (float*)d_out;

  const int N = in_sizes[0] / 128;
  const int E = in_sizes[2] / 2;
  const int G1 = (N + GS - 1) >> GSH;
  const int G  = 2 * G1;

  char* ws = (char*)d_ws;
  size_t off = 0;
  auto alloc = [&](size_t bytes) -> void* {
    void* ptr = ws + off;
    off += (bytes + 255) & ~(size_t)255;
    return ptr;
  };
  float* h0   = (float*)alloc((size_t)N * 128 * sizeof(float));
  float* h1   = (float*)alloc((size_t)N * 128 * sizeof(float));
  float* ag0  = (float*)alloc((size_t)N * 128 * sizeof(float));
  float* ag1  = (float*)alloc((size_t)N * 128 * sizeof(float));
  int* pairs  = (int*)alloc((size_t)G * SCAP * sizeof(int));
  int* offs   = (int*)alloc((size_t)(2 * N) * sizeof(int));
  int* counts = (int*)alloc((size_t)(2 * N) * sizeof(int));
  int* gcur   = (int*)alloc((size_t)(G + 8) * sizeof(int));
  float* pbuf = (float*)alloc(2 * 64 * 64 * sizeof(float));
  (void)ws_size; (void)n_in; (void)out_size;

  // ---- CSR build ----
  hipMemsetAsync(gcur, 0, (size_t)(G + 8) * sizeof(int), stream);
  {
    dim3 gb((E + 4095) / 4096, 2);
    bin_kernel<<<gb, 1024, 0, stream>>>(e1, e1 + E, e2, e2 + E, gcur, pairs, E, G1);
    dim3 gr(G1, 2);
    refine_kernel<<<gr, 1024, 0, stream>>>(gcur, pairs, offs, counts, N, G1);
  }

  // layer 1
  {
    dim3 gg((N + 63) / 64, 2);
    gemm2_kernel<128><<<gg, 256, 0, stream>>>(x1, x2, W1a, W2a, b1a, b2a, h0, h1, N);
  }
  {
    dim3 ga((N + 3) / 4, 4);
    agg128_kernel<<<ga, 256, 0, stream>>>(h0, h1, offs, counts, pairs,
                                          g1a, be1a, g2a, be2a, ag0, ag1, N);
  }
  // layer 2
  {
    dim3 gg((N + 63) / 64, 2);
    gemm2_kernel<64><<<gg, 256, 0, stream>>>(ag0, ag1, W1b, W2b, b1b, b2b, h0, h1, N);
  }
  {
    dim3 ga((N + 3) / 4, 2);
    agg64_kernel<<<ga, 256, 0, stream>>>(h0, h1, offs, counts, pairs,
                                         g1b, be1b, g2b, be2b, ag0, ag1, N);
  }
  // pool + head
  {
    dim3 gp(64, 2);
    pool2_kernel<<<gp, 1024, 0, stream>>>(ag0, ag1, seg1, seg2, pbuf, N);
  }
  head_kernel<<<1, 512, 0, stream>>>(pbuf, Wd, bd, Wo, bo, out);
}